// Round 6
// baseline (198.471 us; speedup 1.0000x reference)
//
#include <hip/hip_runtime.h>
#include <math.h>

// ---- problem constants ----
constexpr int BATCH = 32;
constexpr int LEN   = 240000;
constexpr int HOPS  = 160;
constexpr int T     = 1501;    // LEN/HOP + 1
constexpr int TOUT  = 1504;    // padded to 8
constexpr int NMEL  = 80;
constexpr int NBIN  = 257;
constexpr int CMAX  = 20;      // max bins per mel row (true max = 18)
constexpr int WSTR  = 21;      // LDS weight stride (f32), coprime with 32
constexpr float PRE     = 0.97f;
constexpr float LOG_EPS = 5.9604644775390625e-08f;  // 2^-24
constexpr float STD_EPS = 1e-5f;
constexpr float BLANK_V = 27.0f;

constexpr size_t LOGMEL_ELTS = (size_t)BATCH * T * NMEL;  // [b][t][m]

// ---- GEMM geometry: C[48032 x 512] = A[frames x 320] * B^T ----
constexpr int BM    = 64;      // frames per block
constexpr int BN    = 512;     // cos 0..256 ++ sin 1..255
constexpr int BK    = 32;
constexpr int NSTEP = 10;      // 320 / 32
constexpr int CBLK  = 24;      // 24 x 64 = 1536 >= 1501 frames per batch
constexpr int BSTR  = 40;      // LDS B row stride (bf16) - 16B aligned, 2-way banks
constexpr int ASTR  = 40;      // LDS A row stride (bf16)
constexpr int PSTR  = 260;     // LDS P row stride (f32)

typedef __attribute__((ext_vector_type(8))) short bf16x8;
typedef __attribute__((ext_vector_type(4))) float f32x4;

__device__ __forceinline__ unsigned short f2bf(float f) {   // RNE f32->bf16
  unsigned u = __float_as_uint(f);
  u = (u + 0x7FFFu + ((u >> 16) & 1u)) >> 16;
  return (unsigned short)u;
}
__device__ __forceinline__ int reflect_idx(int p) {
  p = p < 0 ? -p : p;
  return p >= LEN ? 2 * LEN - 2 - p : p;
}
__device__ __forceinline__ float yval(const float* xb, int p) {
  int r = reflect_idx(p);
  return (r == 0) ? xb[0] : (xb[r] - PRE * xb[r - 1]);
}
__device__ __forceinline__ int read_n(const int* xn32, int b) {
  // xn declared int64 but may land as int32; lengths >=160001 so int64's
  // high word (elem 1) is 0 while int32 elem 1 >= 160000.
  int probe = xn32[1];
  int v = (probe == 0) ? xn32[2 * b] : xn32[b];
  return v / HOPS + 1;
}

// ---------------------------------------------------------------------------
// k_prep: one block per mel row; ballot-scan contiguous support; zero ps.
// ---------------------------------------------------------------------------
__global__ __launch_bounds__(64) void k_prep(const float* __restrict__ fb,
                                             int* __restrict__ lc,
                                             float* __restrict__ wg,
                                             float* __restrict__ ps) {
  const int m = blockIdx.x;
  const int l = threadIdx.x;
  ps[m * 64 + l] = 0.f;                       // 80*64 = 5120 accumulators
  int first = 1 << 20, last = -1;
  for (int it = 0; it < 5; ++it) {
    int f = it * 64 + l;
    float w = (f < NBIN) ? fb[m * NBIN + f] : 0.f;
    unsigned long long mk = __ballot(w != 0.f);
    if (mk) {
      int lo = __ffsll(mk) - 1;
      int hi = 63 - __clzll(mk);
      if (first > NBIN) first = it * 64 + lo;
      last = it * 64 + hi;
    }
  }
  int cnt = (last >= first) ? last - first + 1 : 0;
  if (cnt > CMAX) cnt = CMAX;
  if (first > NBIN) first = 0;
  if (l == 0) lc[m] = first | (cnt << 16);
  if (l < CMAX) wg[m * CMAX + l] = (l < cnt) ? fb[m * NBIN + first + l] : 0.f;
}

// ---------------------------------------------------------------------------
// k_bmat: windowed-DFT matrix, bf16, laid out as 10 K-slices [s][n=512][kl=32]
// rows 0..256 = win*cos(2*pi*k*w/512); rows 257..511 = win*sin (k=1..255).
// Integer-mod phase => exact range reduction.
// ---------------------------------------------------------------------------
__global__ __launch_bounds__(256) void k_bmat(unsigned short* __restrict__ Bg) {
  int e = blockIdx.x * 256 + threadIdx.x;     // < 163840
  int s  = e >> 14;
  int n  = (e >> 5) & 511;
  int kl = e & 31;
  int j  = s * 32 + kl;                       // tap index 0..319 (w = j+96)
  float win = 0.5f - 0.5f * __cosf((float)j * (6.283185307179586f / 320.f));
  int bin = (n < 257) ? n : n - 256;
  int ph  = (bin * (j + 96)) & 511;           // exact mod-512 phase
  float ang = (float)ph * (6.283185307179586f / 512.f);
  float tr  = (n < 257) ? __cosf(ang) : __sinf(ang);
  Bg[e] = f2bf(win * tr);
}

// ---------------------------------------------------------------------------
// k_dft: per block, 64 frames x 512 DFT outputs via mfma_f32_16x16x32_bf16,
// K=320 in 10 steps (reg-prefetched staging). Epilogue: power (Xr^2+Xi^2)
// into LDS P, CSR mel, log, masked S/S2 atomics to ps.
// Wave w (8 waves): cols 64w..64w+63; all waves cover all 64 frames.
// ---------------------------------------------------------------------------
__global__ __launch_bounds__(512, 4) void k_dft(const float* __restrict__ x,
    const int* __restrict__ lc, const float* __restrict__ wg,
    const int* __restrict__ xn32, const unsigned short* __restrict__ Bg,
    float* __restrict__ logmel, float* __restrict__ ps) {
  __shared__ float swg[NMEL * WSTR];
  __shared__ int   slc[NMEL];
  __shared__ float red[2 * 4 * NMEL];               // S[4][80] ++ Q[4][80]
  __shared__ __align__(16) char uni[PSTR * BM * 4]; // 65 KB union region

  unsigned short* Bl = (unsigned short*)uni;                    // [512][BSTR]
  unsigned short* Al = (unsigned short*)(uni + 512 * BSTR * 2); // [64][ASTR]
  float* P = (float*)uni;                                       // [64][PSTR]

  const int tid = threadIdx.x;
  const int wid = tid >> 6;
  const int l   = tid & 63;

  for (int i = tid; i < NMEL * CMAX; i += 512)
    swg[(i / CMAX) * WSTR + (i % CMAX)] = wg[i];
  if (tid < NMEL) slc[tid] = lc[tid];

  const int b  = blockIdx.x & 31;      // batch (bid%8 locality on XCDs)
  const int c  = blockIdx.x >> 5;      // frame-chunk 0..23
  const int t0 = c * BM;
  const float* xb = x + (size_t)b * LEN;
  const int nb = read_n(xn32, b);
  const bool slow = (c == 0) || (c == CBLK - 1);   // reflect-edge blocks

  const int arow = tid >> 3;           // 0..63 (frame row for A staging)
  const int q7   = tid & 7;            // quarter-of-8 within row
  const int sbase = 160 * (t0 - 1);
  const uint4* Bg4 = (const uint4*)Bg;

  // ---- prologue: stage K-step 0 ----
  {
    uint4 bq0[4];
    #pragma unroll
    for (int p = 0; p < 4; ++p) bq0[p] = Bg4[tid + 512 * p];
    ushort4 a4;
    if (!slow) {
      int p0 = sbase + 160 * arow + 4 * q7;
      const float4 xa = *(const float4*)(xb + p0);
      float xm = xb[p0 - 1];
      a4.x = f2bf(xa.x - PRE * xm);
      a4.y = f2bf(xa.y - PRE * xa.x);
      a4.z = f2bf(xa.z - PRE * xa.y);
      a4.w = f2bf(xa.w - PRE * xa.z);
    } else {
      int p0 = sbase + 160 * arow + 4 * q7;
      a4.x = f2bf(yval(xb, p0));     a4.y = f2bf(yval(xb, p0 + 1));
      a4.z = f2bf(yval(xb, p0 + 2)); a4.w = f2bf(yval(xb, p0 + 3));
    }
    #pragma unroll
    for (int p = 0; p < 4; ++p) {
      int g = tid + 512 * p;
      *(uint4*)&Bl[(g >> 2) * BSTR + (g & 3) * 8] = bq0[p];
    }
    *(ushort4*)&Al[arow * ASTR + 4 * q7] = a4;
  }
  __syncthreads();

  f32x4 acc[4][4];
  const f32x4 zz = {0.f, 0.f, 0.f, 0.f};
  #pragma unroll
  for (int it = 0; it < 4; ++it)
    #pragma unroll
    for (int jt = 0; jt < 4; ++jt) acc[it][jt] = zz;

  // ---- K loop ----
  uint4 bq[4];
  float4 xa; float xm = 0.f;
  for (int s = 0; s < NSTEP; ++s) {
    const bool pf = (s + 1 < NSTEP);
    if (pf) {                                   // issue next-slice loads early
      #pragma unroll
      for (int p = 0; p < 4; ++p) bq[p] = Bg4[(s + 1) * 2048 + tid + 512 * p];
      if (!slow) {
        int p0 = sbase + 160 * arow + 32 * (s + 1) + 4 * q7;
        xa = *(const float4*)(xb + p0);
        xm = xb[p0 - 1];
      }
    }
    // compute step s
    bf16x8 af[4];
    #pragma unroll
    for (int it = 0; it < 4; ++it)
      af[it] = *(const bf16x8*)&Al[(16 * it + (l & 15)) * ASTR + (l >> 4) * 8];
    #pragma unroll
    for (int jt = 0; jt < 4; ++jt) {
      bf16x8 bf = *(const bf16x8*)&Bl[(64 * wid + 16 * jt + (l & 15)) * BSTR + (l >> 4) * 8];
      #pragma unroll
      for (int it = 0; it < 4; ++it)
        acc[it][jt] = __builtin_amdgcn_mfma_f32_16x16x32_bf16(af[it], bf, acc[it][jt], 0, 0, 0);
    }
    __syncthreads();
    if (pf) {
      ushort4 a4;
      if (!slow) {
        a4.x = f2bf(xa.x - PRE * xm);
        a4.y = f2bf(xa.y - PRE * xa.x);
        a4.z = f2bf(xa.z - PRE * xa.y);
        a4.w = f2bf(xa.w - PRE * xa.z);
      } else {
        int p0 = sbase + 160 * arow + 32 * (s + 1) + 4 * q7;
        a4.x = f2bf(yval(xb, p0));     a4.y = f2bf(yval(xb, p0 + 1));
        a4.z = f2bf(yval(xb, p0 + 2)); a4.w = f2bf(yval(xb, p0 + 3));
      }
      #pragma unroll
      for (int p = 0; p < 4; ++p) {
        int g = tid + 512 * p;
        *(uint4*)&Bl[(g >> 2) * BSTR + (g & 3) * 8] = bq[p];
      }
      *(ushort4*)&Al[arow * ASTR + 4 * q7] = a4;
      __syncthreads();
    }
  }
  __syncthreads();   // all frag reads done; uni becomes P

  // ---- power: phase 1 writes Xr^2 (cols <= 256) ----
  #pragma unroll
  for (int it = 0; it < 4; ++it) {
    int fr = 16 * it + (l >> 4) * 4;
    #pragma unroll
    for (int jt = 0; jt < 4; ++jt) {
      int col = 64 * wid + 16 * jt + (l & 15);
      if (col <= 256) {
        #pragma unroll
        for (int r = 0; r < 4; ++r) {
          float v = acc[it][jt][r];
          P[(fr + r) * PSTR + col] = v * v;
        }
      }
    }
  }
  __syncthreads();
  // ---- phase 2 adds Xi^2 (cols >= 257 -> bin = col-256) ----
  #pragma unroll
  for (int it = 0; it < 4; ++it) {
    int fr = 16 * it + (l >> 4) * 4;
    #pragma unroll
    for (int jt = 0; jt < 4; ++jt) {
      int col = 64 * wid + 16 * jt + (l & 15);
      if (col >= 257) {
        int bin = col - 256;
        #pragma unroll
        for (int r = 0; r < 4; ++r) {
          float v = acc[it][jt][r];
          P[(fr + r) * PSTR + bin] += v * v;
        }
      }
    }
  }
  __syncthreads();

  // ---- CSR mel + log + masked stats (threads 0..319: m = tid%80) ----
  const size_t lbase = ((size_t)b * T + t0) * NMEL;
  if (tid < 320) {
    int m = tid % 80, fc = tid / 80;
    int lo = slc[m] & 0xffff;
    const float* pw = &swg[m * WSTR];
    float lS = 0.f, lQ = 0.f;
    for (int ff = 0; ff < 16; ++ff) {
      int f = fc * 16 + ff;
      const float* pp = &P[f * PSTR + lo];
      float a_ = 0.f;
      #pragma unroll
      for (int j = 0; j < CMAX; ++j) a_ += pp[j] * pw[j];
      float lv = __logf(a_ + LOG_EPS);
      int t = t0 + f;
      if (t < T) logmel[lbase + (size_t)f * NMEL + m] = lv;
      if (t < nb) { lS += lv; lQ += lv * lv; }
    }
    red[fc * 80 + m] = lS;
    red[320 + fc * 80 + m] = lQ;
  }
  __syncthreads();
  if (tid < NMEL) {
    float S = red[tid] + red[80 + tid] + red[160 + tid] + red[240 + tid];
    float Q = red[320 + tid] + red[400 + tid] + red[480 + tid] + red[560 + tid];
    atomicAdd(&ps[b * 160 + tid], S);
    atomicAdd(&ps[b * 160 + 80 + tid], Q);
  }
}

// ---------------------------------------------------------------------------
// k_apply: finalize stats, normalize + transpose [b][t][m] -> out[b][m][t],
// zero invalid, BLANK pad; 64-wide t tiles, float4 both directions.
// ---------------------------------------------------------------------------
__global__ __launch_bounds__(256) void k_apply(const float* __restrict__ logmel,
    const float* __restrict__ ps, const int* __restrict__ xn32,
    float* __restrict__ out, float* __restrict__ outseq) {
  const int bid = blockIdx.x;
  const int b = bid / 24, c = bid % 24;
  const int tbase = c * 64;
  __shared__ float tile[64 * 81];
  __shared__ float smean[80], sistd[80];
  const int tid = threadIdx.x;
  const int n = read_n(xn32, b);
  if (tid < 80) {
    float S = ps[b * 160 + tid], S2 = ps[b * 160 + 80 + tid];
    float fn = (float)n;
    float mean = S / fn;
    float var = (S2 - fn * mean * mean) / (fn - 1.f);
    var = var < 0.f ? 0.f : var;
    smean[tid] = mean;
    sistd[tid] = 1.f / (sqrtf(var) + STD_EPS);
  }
  __syncthreads();

  for (int e = tid; e < 1280; e += 256) {      // 64 t x 20 float4-of-m
    int tt = e / 20, v = e % 20;
    int t = tbase + tt;
    int m0 = 4 * v;
    float4 val;
    if (t >= T)      val = make_float4(BLANK_V, BLANK_V, BLANK_V, BLANK_V);
    else if (t >= n) val = make_float4(0.f, 0.f, 0.f, 0.f);
    else {
      const float4 g = *(const float4*)&logmel[((size_t)b * T + t) * NMEL + m0];
      val.x = (g.x - smean[m0])     * sistd[m0];
      val.y = (g.y - smean[m0 + 1]) * sistd[m0 + 1];
      val.z = (g.z - smean[m0 + 2]) * sistd[m0 + 2];
      val.w = (g.w - smean[m0 + 3]) * sistd[m0 + 3];
    }
    float* tp = &tile[tt * 81 + m0];
    tp[0] = val.x; tp[1] = val.y; tp[2] = val.z; tp[3] = val.w;
  }
  __syncthreads();
  for (int e = tid; e < 1280; e += 256) {      // 80 m x 16 float4-of-t
    int m = e >> 4, v = e & 15;
    int tt0 = 4 * v;
    int t = tbase + tt0;
    if (t < TOUT) {
      float4 o;
      o.x = tile[(tt0    ) * 81 + m];
      o.y = tile[(tt0 + 1) * 81 + m];
      o.z = tile[(tt0 + 2) * 81 + m];
      o.w = tile[(tt0 + 3) * 81 + m];
      *(float4*)&out[((size_t)b * NMEL + m) * TOUT + t] = o;
    }
  }
  if (c == 0 && tid == 0) outseq[b] = (float)n;
}

// ---------------------------------------------------------------------------
extern "C" void kernel_launch(void* const* d_in, const int* in_sizes, int n_in,
                              void* d_out, int out_size, void* d_ws, size_t ws_size,
                              hipStream_t stream) {
  const float* x  = (const float*)d_in[0];
  const int*   xn = (const int*)d_in[1];
  const float* fb = (const float*)d_in[2];

  float* out    = (float*)d_out;
  float* outseq = out + (size_t)BATCH * NMEL * TOUT;

  float* logmel = (float*)d_ws;
  int*   lc = (int*)(logmel + LOGMEL_ELTS);
  float* wg = (float*)(lc + NMEL);                  // 80*CMAX
  float* ps = wg + NMEL * CMAX;                     // 32*160 accumulators
  unsigned short* Bg = (unsigned short*)(ps + 32 * 160);  // 10*512*32 bf16

  k_prep <<<NMEL, 64, 0, stream>>>(fb, lc, wg, ps);
  k_bmat <<<640, 256, 0, stream>>>(Bg);
  k_dft  <<<BATCH * CBLK, 512, 0, stream>>>(x, lc, wg, xn, Bg, logmel, ps);
  k_apply<<<BATCH * CBLK, 256, 0, stream>>>(logmel, ps, xn, out, outseq);
}

// Round 8
// 138.214 us; speedup vs baseline: 1.4360x; 1.4360x over previous
//
#include <hip/hip_runtime.h>
#include <math.h>

// ---- problem constants ----
constexpr int BATCH = 32;
constexpr int LEN   = 240000;
constexpr int HOPS  = 160;
constexpr int T     = 1501;    // LEN/HOP + 1
constexpr int TOUT  = 1504;    // padded to 8
constexpr int NMEL  = 80;
constexpr int NBIN  = 257;
constexpr int CMAX  = 20;      // max bins per mel row (true max = 18)
constexpr int WSTR  = 21;      // LDS weight stride (f32), coprime with 32
constexpr float PRE     = 0.97f;
constexpr float LOG_EPS = 5.9604644775390625e-08f;  // 2^-24
constexpr float STD_EPS = 1e-5f;
constexpr float BLANK_V = 27.0f;

constexpr size_t LOGMEL_ELTS = (size_t)BATCH * T * NMEL;  // [b][t][m]

// ---- GEMM geometry: C[48032 x 512] = A[frames x 320] * B^T ----
constexpr int BM    = 64;      // frames per block
constexpr int NSTEP = 10;      // 320 / 32
constexpr int CBLK  = 24;      // 24 x 64 = 1536 >= 1501 frames per batch
constexpr int BSTR  = 40;      // LDS B row stride (bf16): 80B rows, 16B aligned
constexpr int ASTR  = 40;      // LDS A row stride (bf16)
constexpr int PSTR  = 260;     // LDS P row stride (f32)

typedef __attribute__((ext_vector_type(8))) short bf16x8;
typedef __attribute__((ext_vector_type(4))) float f32x4;

__device__ __forceinline__ unsigned short f2bf(float f) {   // RNE f32->bf16
  unsigned u = __float_as_uint(f);
  u = (u + 0x7FFFu + ((u >> 16) & 1u)) >> 16;
  return (unsigned short)u;
}
__device__ __forceinline__ int reflect_idx(int p) {
  p = p < 0 ? -p : p;
  return p >= LEN ? 2 * LEN - 2 - p : p;
}
__device__ __forceinline__ float yval(const float* xb, int p) {
  int r = reflect_idx(p);
  return (r == 0) ? xb[0] : (xb[r] - PRE * xb[r - 1]);
}
__device__ __forceinline__ int read_n(const int* xn32, int b) {
  // xn declared int64 but may land as int32; lengths >=160001 so int64's
  // high word (elem 1) is 0 while int32 elem 1 >= 160000.
  int probe = xn32[1];
  int v = (probe == 0) ? xn32[2 * b] : xn32[b];
  return v / HOPS + 1;
}

// ---------------------------------------------------------------------------
// k_prep: one block per mel row; ballot-scan contiguous support; zero ps.
// ---------------------------------------------------------------------------
__global__ __launch_bounds__(64) void k_prep(const float* __restrict__ fb,
                                             int* __restrict__ lc,
                                             float* __restrict__ wg,
                                             float* __restrict__ ps) {
  const int m = blockIdx.x;
  const int l = threadIdx.x;
  ps[m * 64 + l] = 0.f;                       // 80*64 = 5120 accumulators
  int first = 1 << 20, last = -1;
  for (int it = 0; it < 5; ++it) {
    int f = it * 64 + l;
    float w = (f < NBIN) ? fb[m * NBIN + f] : 0.f;
    unsigned long long mk = __ballot(w != 0.f);
    if (mk) {
      int lo = __ffsll(mk) - 1;
      int hi = 63 - __clzll(mk);
      if (first > NBIN) first = it * 64 + lo;
      last = it * 64 + hi;
    }
  }
  int cnt = (last >= first) ? last - first + 1 : 0;
  if (cnt > CMAX) cnt = CMAX;
  if (first > NBIN) first = 0;
  if (l == 0) lc[m] = first | (cnt << 16);
  if (l < CMAX) wg[m * CMAX + l] = (l < cnt) ? fb[m * NBIN + first + l] : 0.f;
}

// ---------------------------------------------------------------------------
// k_bmat: windowed-DFT matrix, bf16, laid out as 10 K-slices [s][n=512][kl=32]
// rows 0..256 = win*cos(2*pi*k*w/512); rows 257..511 = win*sin (k=1..255).
// Integer-mod phase => exact range reduction.
// ---------------------------------------------------------------------------
__global__ __launch_bounds__(256) void k_bmat(unsigned short* __restrict__ Bg) {
  int e = blockIdx.x * 256 + threadIdx.x;     // < 163840
  int s  = e >> 14;
  int n  = (e >> 5) & 511;
  int kl = e & 31;
  int j  = s * 32 + kl;                       // tap index 0..319 (w = j+96)
  float win = 0.5f - 0.5f * __cosf((float)j * (6.283185307179586f / 320.f));
  int bin = (n < 257) ? n : n - 256;
  int ph  = (bin * (j + 96)) & 511;           // exact mod-512 phase
  float ang = (float)ph * (6.283185307179586f / 512.f);
  float tr  = (n < 257) ? __cosf(ang) : __sinf(ang);
  Bg[e] = f2bf(win * tr);
}

// ---------------------------------------------------------------------------
// k_dft: per block, 64 frames x 512 DFT outputs via mfma_f32_16x16x32_bf16,
// K=320 in 10 steps. 2-phase staging (no B register prefetch -> spill-free;
// only A keeps a 5-reg prefetch to hide cold-HBM x loads under MFMA).
// Epilogue: power into LDS P, CSR mel, log, masked S/S2 atomics.
// ---------------------------------------------------------------------------
__global__ __launch_bounds__(512, 4) void k_dft(const float* __restrict__ x,
    const int* __restrict__ lc, const float* __restrict__ wg,
    const int* __restrict__ xn32, const unsigned short* __restrict__ Bg,
    float* __restrict__ logmel, float* __restrict__ ps) {
  __shared__ float swg[NMEL * WSTR];
  __shared__ int   slc[NMEL];
  __shared__ float red[2 * 4 * NMEL];               // S[4][80] ++ Q[4][80]
  __shared__ __align__(16) char uni[PSTR * BM * 4]; // 66.5 KB union region

  unsigned short* Bl = (unsigned short*)uni;                    // [512][BSTR]
  unsigned short* Al = (unsigned short*)(uni + 512 * BSTR * 2); // [64][ASTR]
  float* P = (float*)uni;                                       // [64][PSTR]

  const int tid = threadIdx.x;
  const int wid = tid >> 6;
  const int l   = tid & 63;

  for (int i = tid; i < NMEL * CMAX; i += 512)
    swg[(i / CMAX) * WSTR + (i % CMAX)] = wg[i];
  if (tid < NMEL) slc[tid] = lc[tid];

  const int b  = blockIdx.x & 31;      // batch
  const int c  = blockIdx.x >> 5;      // frame-chunk 0..23
  const int t0 = c * BM;
  const float* xb = x + (size_t)b * LEN;
  const int nb = read_n(xn32, b);
  const bool slow = (c == 0) || (c == CBLK - 1);   // reflect-edge blocks

  const int arow = tid >> 3;           // 0..63 (frame row for A staging)
  const int q7   = tid & 7;
  const int sbase = 160 * (t0 - 1);
  const uint4* Bg4 = (const uint4*)Bg;

  // ---- stage K-step 0 (B + A) ----
  {
    #pragma unroll
    for (int p = 0; p < 4; ++p) {
      uint4 bv = Bg4[tid + 512 * p];
      int g = tid + 512 * p;
      *(uint4*)&Bl[(g >> 2) * BSTR + (g & 3) * 8] = bv;
    }
    int p0 = sbase + 160 * arow + 4 * q7;
    ushort4 a4;
    if (!slow) {
      const float4 xa0 = *(const float4*)(xb + p0);
      float xm0 = xb[p0 - 1];
      a4.x = f2bf(xa0.x - PRE * xm0);
      a4.y = f2bf(xa0.y - PRE * xa0.x);
      a4.z = f2bf(xa0.z - PRE * xa0.y);
      a4.w = f2bf(xa0.w - PRE * xa0.z);
    } else {
      a4.x = f2bf(yval(xb, p0));     a4.y = f2bf(yval(xb, p0 + 1));
      a4.z = f2bf(yval(xb, p0 + 2)); a4.w = f2bf(yval(xb, p0 + 3));
    }
    *(ushort4*)&Al[arow * ASTR + 4 * q7] = a4;
  }
  __syncthreads();

  f32x4 acc[4][4];
  const f32x4 zz = {0.f, 0.f, 0.f, 0.f};
  #pragma unroll
  for (int it = 0; it < 4; ++it)
    #pragma unroll
    for (int jt = 0; jt < 4; ++jt) acc[it][jt] = zz;

  // ---- K loop: compute s; stage s+1 between barriers (A reg-prefetched) ----
  for (int s = 0; s < NSTEP; ++s) {
    const bool pf = (s + 1 < NSTEP);
    float4 xa; float xm = 0.f;
    if (pf && !slow) {                 // issue A loads early (hide under MFMA)
      int p0 = sbase + 160 * arow + 32 * (s + 1) + 4 * q7;
      xa = *(const float4*)(xb + p0);
      xm = xb[p0 - 1];
    }
    // compute step s
    bf16x8 af[4];
    #pragma unroll
    for (int it = 0; it < 4; ++it)
      af[it] = *(const bf16x8*)&Al[(16 * it + (l & 15)) * ASTR + (l >> 4) * 8];
    #pragma unroll
    for (int jt = 0; jt < 4; ++jt) {
      bf16x8 bfr = *(const bf16x8*)&Bl[(64 * wid + 16 * jt + (l & 15)) * BSTR + (l >> 4) * 8];
      #pragma unroll
      for (int it = 0; it < 4; ++it)
        acc[it][jt] = __builtin_amdgcn_mfma_f32_16x16x32_bf16(af[it], bfr, acc[it][jt], 0, 0, 0);
    }
    __syncthreads();                   // frag reads of step s done
    if (pf) {
      // B slice s+1: direct L2 -> LDS (no register carry across the loop)
      #pragma unroll
      for (int p = 0; p < 4; ++p) {
        uint4 bv = Bg4[(s + 1) * 2048 + tid + 512 * p];
        int g = tid + 512 * p;
        *(uint4*)&Bl[(g >> 2) * BSTR + (g & 3) * 8] = bv;
      }
      ushort4 a4;
      if (!slow) {
        a4.x = f2bf(xa.x - PRE * xm);
        a4.y = f2bf(xa.y - PRE * xa.x);
        a4.z = f2bf(xa.z - PRE * xa.y);
        a4.w = f2bf(xa.w - PRE * xa.z);
      } else {
        int p0 = sbase + 160 * arow + 32 * (s + 1) + 4 * q7;
        a4.x = f2bf(yval(xb, p0));     a4.y = f2bf(yval(xb, p0 + 1));
        a4.z = f2bf(yval(xb, p0 + 2)); a4.w = f2bf(yval(xb, p0 + 3));
      }
      *(ushort4*)&Al[arow * ASTR + 4 * q7] = a4;
      __syncthreads();
    }
  }
  __syncthreads();   // all frag reads done; uni becomes P

  // ---- power: phase 1 writes Xr^2 (cols <= 256) ----
  #pragma unroll
  for (int it = 0; it < 4; ++it) {
    int fr = 16 * it + (l >> 4) * 4;
    #pragma unroll
    for (int jt = 0; jt < 4; ++jt) {
      int col = 64 * wid + 16 * jt + (l & 15);
      if (col <= 256) {
        #pragma unroll
        for (int r = 0; r < 4; ++r) {
          float v = acc[it][jt][r];
          P[(fr + r) * PSTR + col] = v * v;
        }
      }
    }
  }
  __syncthreads();
  // ---- phase 2 adds Xi^2 (cols >= 257 -> bin = col-256) ----
  #pragma unroll
  for (int it = 0; it < 4; ++it) {
    int fr = 16 * it + (l >> 4) * 4;
    #pragma unroll
    for (int jt = 0; jt < 4; ++jt) {
      int col = 64 * wid + 16 * jt + (l & 15);
      if (col >= 257) {
        int bin = col - 256;
        #pragma unroll
        for (int r = 0; r < 4; ++r) {
          float v = acc[it][jt][r];
          P[(fr + r) * PSTR + bin] += v * v;
        }
      }
    }
  }
  __syncthreads();

  // ---- CSR mel + log + masked stats (threads 0..319: m = tid%80) ----
  const size_t lbase = ((size_t)b * T + t0) * NMEL;
  if (tid < 320) {
    int m = tid % 80, fc = tid / 80;
    int lo = slc[m] & 0xffff;
    const float* pw = &swg[m * WSTR];
    float lS = 0.f, lQ = 0.f;
    for (int ff = 0; ff < 16; ++ff) {
      int f = fc * 16 + ff;
      const float* pp = &P[f * PSTR + lo];
      float a_ = 0.f;
      #pragma unroll
      for (int j = 0; j < CMAX; ++j) a_ += pp[j] * pw[j];
      float lv = __logf(a_ + LOG_EPS);
      int t = t0 + f;
      if (t < T) logmel[lbase + (size_t)f * NMEL + m] = lv;
      if (t < nb) { lS += lv; lQ += lv * lv; }
    }
    red[fc * 80 + m] = lS;
    red[320 + fc * 80 + m] = lQ;
  }
  __syncthreads();
  if (tid < NMEL) {
    float S = red[tid] + red[80 + tid] + red[160 + tid] + red[240 + tid];
    float Q = red[320 + tid] + red[400 + tid] + red[480 + tid] + red[560 + tid];
    atomicAdd(&ps[b * 160 + tid], S);
    atomicAdd(&ps[b * 160 + 80 + tid], Q);
  }
}

// ---------------------------------------------------------------------------
// k_apply: finalize stats, normalize + transpose [b][t][m] -> out[b][m][t],
// zero invalid, BLANK pad; 64-wide t tiles, float4 both directions.
// ---------------------------------------------------------------------------
__global__ __launch_bounds__(256) void k_apply(const float* __restrict__ logmel,
    const float* __restrict__ ps, const int* __restrict__ xn32,
    float* __restrict__ out, float* __restrict__ outseq) {
  const int bid = blockIdx.x;
  const int b = bid / 24, c = bid % 24;
  const int tbase = c * 64;
  __shared__ float tile[64 * 81];
  __shared__ float smean[80], sistd[80];
  const int tid = threadIdx.x;
  const int n = read_n(xn32, b);
  if (tid < 80) {
    float S = ps[b * 160 + tid], S2 = ps[b * 160 + 80 + tid];
    float fn = (float)n;
    float mean = S / fn;
    float var = (S2 - fn * mean * mean) / (fn - 1.f);
    var = var < 0.f ? 0.f : var;
    smean[tid] = mean;
    sistd[tid] = 1.f / (sqrtf(var) + STD_EPS);
  }
  __syncthreads();

  for (int e = tid; e < 1280; e += 256) {      // 64 t x 20 float4-of-m
    int tt = e / 20, v = e % 20;
    int t = tbase + tt;
    int m0 = 4 * v;
    float4 val;
    if (t >= T)      val = make_float4(BLANK_V, BLANK_V, BLANK_V, BLANK_V);
    else if (t >= n) val = make_float4(0.f, 0.f, 0.f, 0.f);
    else {
      const float4 g = *(const float4*)&logmel[((size_t)b * T + t) * NMEL + m0];
      val.x = (g.x - smean[m0])     * sistd[m0];
      val.y = (g.y - smean[m0 + 1]) * sistd[m0 + 1];
      val.z = (g.z - smean[m0 + 2]) * sistd[m0 + 2];
      val.w = (g.w - smean[m0 + 3]) * sistd[m0 + 3];
    }
    float* tp = &tile[tt * 81 + m0];
    tp[0] = val.x; tp[1] = val.y; tp[2] = val.z; tp[3] = val.w;
  }
  __syncthreads();
  for (int e = tid; e < 1280; e += 256) {      // 80 m x 16 float4-of-t
    int m = e >> 4, v = e & 15;
    int tt0 = 4 * v;
    int t = tbase + tt0;
    if (t < TOUT) {
      float4 o;
      o.x = tile[(tt0    ) * 81 + m];
      o.y = tile[(tt0 + 1) * 81 + m];
      o.z = tile[(tt0 + 2) * 81 + m];
      o.w = tile[(tt0 + 3) * 81 + m];
      *(float4*)&out[((size_t)b * NMEL + m) * TOUT + t] = o;
    }
  }
  if (c == 0 && tid == 0) outseq[b] = (float)n;
}

// ---------------------------------------------------------------------------
extern "C" void kernel_launch(void* const* d_in, const int* in_sizes, int n_in,
                              void* d_out, int out_size, void* d_ws, size_t ws_size,
                              hipStream_t stream) {
  const float* x  = (const float*)d_in[0];
  const int*   xn = (const int*)d_in[1];
  const float* fb = (const float*)d_in[2];

  float* out    = (float*)d_out;
  float* outseq = out + (size_t)BATCH * NMEL * TOUT;

  float* logmel = (float*)d_ws;
  int*   lc = (int*)(logmel + LOGMEL_ELTS);
  float* wg = (float*)(lc + NMEL);                  // 80*CMAX
  float* ps = wg + NMEL * CMAX;                     // 32*160 accumulators
  unsigned short* Bg = (unsigned short*)(ps + 32 * 160);  // 10*512*32 bf16

  k_prep <<<NMEL, 64, 0, stream>>>(fb, lc, wg, ps);
  k_bmat <<<640, 256, 0, stream>>>(Bg);
  k_dft  <<<BATCH * CBLK, 512, 0, stream>>>(x, lc, wg, xn, Bg, logmel, ps);
  k_apply<<<BATCH * CBLK, 256, 0, stream>>>(logmel, ps, xn, out, outseq);
}

// Round 9
// 128.212 us; speedup vs baseline: 1.5480x; 1.0780x over previous
//
#include <hip/hip_runtime.h>
#include <math.h>

// ---- problem constants ----
constexpr int BATCH = 32;
constexpr int LEN   = 240000;
constexpr int HOPS  = 160;
constexpr int T     = 1501;    // LEN/HOP + 1
constexpr int TOUT  = 1504;    // padded to 8
constexpr int NMEL  = 80;
constexpr int NBIN  = 257;
constexpr int CMAX  = 20;      // max bins per mel row (true max = 18)
constexpr int WSTR  = 21;      // LDS weight stride (f32), coprime with 32
constexpr float PRE     = 0.97f;
constexpr float LOG_EPS = 5.9604644775390625e-08f;  // 2^-24
constexpr float STD_EPS = 1e-5f;
constexpr float BLANK_V = 27.0f;

constexpr size_t LOGMEL_ELTS = (size_t)BATCH * T * NMEL;  // [b][t][m]

// ---- GEMM geometry: C[48032 x 512] = A[frames x 320] * B^T ----
constexpr int BM    = 64;      // frames per block
constexpr int NSTEP = 10;      // 320 / 32
constexpr int CBLK  = 24;      // 24 x 64 = 1536 >= 1501 frames per batch
constexpr int ASTR  = 40;      // LDS A row stride (bf16)
constexpr int PSTR  = 260;     // LDS P row stride (f32)

typedef __attribute__((ext_vector_type(8))) short bf16x8;
typedef __attribute__((ext_vector_type(4))) float f32x4;

__device__ __forceinline__ unsigned short f2bf(float f) {   // RNE f32->bf16
  unsigned u = __float_as_uint(f);
  u = (u + 0x7FFFu + ((u >> 16) & 1u)) >> 16;
  return (unsigned short)u;
}
__device__ __forceinline__ int reflect_idx(int p) {
  p = p < 0 ? -p : p;
  return p >= LEN ? 2 * LEN - 2 - p : p;
}
__device__ __forceinline__ float yval(const float* xb, int p) {
  int r = reflect_idx(p);
  return (r == 0) ? xb[0] : (xb[r] - PRE * xb[r - 1]);
}
__device__ __forceinline__ int read_n(const int* xn32, int b) {
  // xn declared int64 but may land as int32; lengths >=160001 so int64's
  // high word (elem 1) is 0 while int32 elem 1 >= 160000.
  int probe = xn32[1];
  int v = (probe == 0) ? xn32[2 * b] : xn32[b];
  return v / HOPS + 1;
}

// ---------------------------------------------------------------------------
// k_setup: blocks 0..79 -> mel-row CSR prep + zero ps; blocks 80..719 ->
// windowed-DFT B matrix in FRAGMENT-LINEAR bf16 layout:
//   Bf[(((s*32 + rg)*64) + l)*8 + d], rg = row-group (wave w, jt -> 4w+jt)
//   lane l supplies row n = 16*rg + (l&15), k = 32*s + 8*(l>>4) + d.
// Rows 0..256 = win*cos(2*pi*n*w/512); rows 257..511 = win*sin((n-256)...).
// ---------------------------------------------------------------------------
__global__ __launch_bounds__(256) void k_setup(const float* __restrict__ fb,
                                               int* __restrict__ lc,
                                               float* __restrict__ wg,
                                               float* __restrict__ ps,
                                               unsigned short* __restrict__ Bf) {
  if (blockIdx.x < 80) {
    const int m = blockIdx.x;
    const int l = threadIdx.x;
    if (l < 64) {
      ps[m * 64 + l] = 0.f;                   // 80*64 = 5120 accumulators
      int first = 1 << 20, last = -1;
      for (int it = 0; it < 5; ++it) {
        int f = it * 64 + l;
        float w = (f < NBIN) ? fb[m * NBIN + f] : 0.f;
        unsigned long long mk = __ballot(w != 0.f);
        if (mk) {
          int lo = __ffsll(mk) - 1;
          int hi = 63 - __clzll(mk);
          if (first > NBIN) first = it * 64 + lo;
          last = it * 64 + hi;
        }
      }
      int cnt = (last >= first) ? last - first + 1 : 0;
      if (cnt > CMAX) cnt = CMAX;
      if (first > NBIN) first = 0;
      if (l == 0) lc[m] = first | (cnt << 16);
      if (l < CMAX) wg[m * CMAX + l] = (l < cnt) ? fb[m * NBIN + first + l] : 0.f;
    }
  } else {
    int e = (blockIdx.x - 80) * 256 + threadIdx.x;   // < 163840
    int d  = e & 7;
    int l  = (e >> 3) & 63;
    int rg = (e >> 9) & 31;
    int s  = e >> 14;
    int n  = 16 * rg + (l & 15);
    int j  = 32 * s + 8 * (l >> 4) + d;              // tap index 0..319
    float win = 0.5f - 0.5f * __cosf((float)j * (6.283185307179586f / 320.f));
    int bin = (n < 257) ? n : n - 256;
    int ph  = (bin * (j + 96)) & 511;                // exact mod-512 phase
    float ang = (float)ph * (6.283185307179586f / 512.f);
    float tr  = (n < 257) ? __cosf(ang) : __sinf(ang);
    Bf[e] = f2bf(win * tr);
  }
}

// ---------------------------------------------------------------------------
// k_dft: 64 frames x 512 DFT outputs per block via mfma_f32_16x16x32_bf16.
// B fragments read DIRECTLY from global (fragment-linear, L2-resident; no
// cross-wave reuse so no LDS staging). A double-buffered in LDS -> ONE
// barrier per K-step. Epilogue: power into LDS P, CSR mel, log, stats.
// ---------------------------------------------------------------------------
__global__ __launch_bounds__(512, 4) void k_dft(const float* __restrict__ x,
    const int* __restrict__ lc, const float* __restrict__ wg,
    const int* __restrict__ xn32, const unsigned short* __restrict__ Bf,
    float* __restrict__ logmel, float* __restrict__ ps) {
  __shared__ float swg[NMEL * WSTR];
  __shared__ int   slc[NMEL];
  __shared__ float red[2 * 4 * NMEL];               // S[4][80] ++ Q[4][80]
  __shared__ __align__(16) char uni[PSTR * BM * 4]; // 66.5 KB union region

  unsigned short* Al = (unsigned short*)uni;        // [2][64][ASTR] dbuf
  float* P = (float*)uni;                           // [64][PSTR]

  const int tid = threadIdx.x;
  const int wid = tid >> 6;
  const int l   = tid & 63;

  for (int i = tid; i < NMEL * CMAX; i += 512)
    swg[(i / CMAX) * WSTR + (i % CMAX)] = wg[i];
  if (tid < NMEL) slc[tid] = lc[tid];

  const int b  = blockIdx.x & 31;      // batch
  const int c  = blockIdx.x >> 5;      // frame-chunk 0..23
  const int t0 = c * BM;
  const float* xb = x + (size_t)b * LEN;
  const int nb = read_n(xn32, b);
  const bool slow = (c == 0) || (c == CBLK - 1);   // reflect-edge blocks

  const int arow = tid >> 3;           // 0..63 (frame row for A staging)
  const int q7   = tid & 7;
  const int sbase = 160 * (t0 - 1);
  const bf16x8* Bf8 = (const bf16x8*)Bf;

  // ---- prologue: stage A step 0 into buf 0 ----
  {
    int p0 = sbase + 160 * arow + 4 * q7;
    ushort4 a4;
    if (!slow) {
      const float4 xa0 = *(const float4*)(xb + p0);
      float xm0 = xb[p0 - 1];
      a4.x = f2bf(xa0.x - PRE * xm0);
      a4.y = f2bf(xa0.y - PRE * xa0.x);
      a4.z = f2bf(xa0.z - PRE * xa0.y);
      a4.w = f2bf(xa0.w - PRE * xa0.z);
    } else {
      a4.x = f2bf(yval(xb, p0));     a4.y = f2bf(yval(xb, p0 + 1));
      a4.z = f2bf(yval(xb, p0 + 2)); a4.w = f2bf(yval(xb, p0 + 3));
    }
    *(ushort4*)&Al[arow * ASTR + 4 * q7] = a4;
  }
  __syncthreads();

  f32x4 acc[4][4];
  const f32x4 zz = {0.f, 0.f, 0.f, 0.f};
  #pragma unroll
  for (int it = 0; it < 4; ++it)
    #pragma unroll
    for (int jt = 0; jt < 4; ++jt) acc[it][jt] = zz;

  // ---- K loop: ONE barrier per step ----
  for (int s = 0; s < NSTEP; ++s) {
    const bool pf = (s + 1 < NSTEP);
    // B fragments for this step: direct global, coalesced 16B/lane
    bf16x8 bfr[4];
    #pragma unroll
    for (int jt = 0; jt < 4; ++jt)
      bfr[jt] = Bf8[(s * 32 + 4 * wid + jt) * 64 + l];
    // A x-prefetch for s+1 (hide HBM/L2 latency under MFMA)
    float4 xa; float xm = 0.f;
    if (pf && !slow) {
      int p0 = sbase + 160 * arow + 32 * (s + 1) + 4 * q7;
      xa = *(const float4*)(xb + p0);
      xm = xb[p0 - 1];
    }
    // MFMA: stream one A frag per it
    const unsigned short* Ab = Al + (s & 1) * (BM * ASTR);
    #pragma unroll
    for (int it = 0; it < 4; ++it) {
      bf16x8 af = *(const bf16x8*)&Ab[(16 * it + (l & 15)) * ASTR + (l >> 4) * 8];
      #pragma unroll
      for (int jt = 0; jt < 4; ++jt)
        acc[it][jt] = __builtin_amdgcn_mfma_f32_16x16x32_bf16(af, bfr[jt], acc[it][jt], 0, 0, 0);
    }
    // stage A[s+1] into the idle buffer
    if (pf) {
      ushort4 a4;
      if (!slow) {
        a4.x = f2bf(xa.x - PRE * xm);
        a4.y = f2bf(xa.y - PRE * xa.x);
        a4.z = f2bf(xa.z - PRE * xa.y);
        a4.w = f2bf(xa.w - PRE * xa.z);
      } else {
        int p0 = sbase + 160 * arow + 32 * (s + 1) + 4 * q7;
        a4.x = f2bf(yval(xb, p0));     a4.y = f2bf(yval(xb, p0 + 1));
        a4.z = f2bf(yval(xb, p0 + 2)); a4.w = f2bf(yval(xb, p0 + 3));
      }
      *(ushort4*)&Al[((s + 1) & 1) * (BM * ASTR) + arow * ASTR + 4 * q7] = a4;
    }
    __syncthreads();
  }

  // ---- power: phase 1 writes Xr^2 (cols <= 256) ----
  #pragma unroll
  for (int it = 0; it < 4; ++it) {
    int fr = 16 * it + (l >> 4) * 4;
    #pragma unroll
    for (int jt = 0; jt < 4; ++jt) {
      int col = 64 * wid + 16 * jt + (l & 15);
      if (col <= 256) {
        #pragma unroll
        for (int r = 0; r < 4; ++r) {
          float v = acc[it][jt][r];
          P[(fr + r) * PSTR + col] = v * v;
        }
      }
    }
  }
  __syncthreads();
  // ---- phase 2 adds Xi^2 (cols >= 257 -> bin = col-256) ----
  #pragma unroll
  for (int it = 0; it < 4; ++it) {
    int fr = 16 * it + (l >> 4) * 4;
    #pragma unroll
    for (int jt = 0; jt < 4; ++jt) {
      int col = 64 * wid + 16 * jt + (l & 15);
      if (col >= 257) {
        int bin = col - 256;
        #pragma unroll
        for (int r = 0; r < 4; ++r) {
          float v = acc[it][jt][r];
          P[(fr + r) * PSTR + bin] += v * v;
        }
      }
    }
  }
  __syncthreads();

  // ---- CSR mel + log + masked stats (threads 0..319: m = tid%80) ----
  const size_t lbase = ((size_t)b * T + t0) * NMEL;
  if (tid < 320) {
    int m = tid % 80, fc = tid / 80;
    int lo = slc[m] & 0xffff;
    const float* pw = &swg[m * WSTR];
    float lS = 0.f, lQ = 0.f;
    for (int ff = 0; ff < 16; ++ff) {
      int f = fc * 16 + ff;
      const float* pp = &P[f * PSTR + lo];
      float a_ = 0.f;
      #pragma unroll
      for (int j = 0; j < CMAX; ++j) a_ += pp[j] * pw[j];
      float lv = __logf(a_ + LOG_EPS);
      int t = t0 + f;
      if (t < T) logmel[lbase + (size_t)f * NMEL + m] = lv;
      if (t < nb) { lS += lv; lQ += lv * lv; }
    }
    red[fc * 80 + m] = lS;
    red[320 + fc * 80 + m] = lQ;
  }
  __syncthreads();
  if (tid < NMEL) {
    float S = red[tid] + red[80 + tid] + red[160 + tid] + red[240 + tid];
    float Q = red[320 + tid] + red[400 + tid] + red[480 + tid] + red[560 + tid];
    atomicAdd(&ps[b * 160 + tid], S);
    atomicAdd(&ps[b * 160 + 80 + tid], Q);
  }
}

// ---------------------------------------------------------------------------
// k_apply: finalize stats, normalize + transpose [b][t][m] -> out[b][m][t],
// zero invalid, BLANK pad; 64-wide t tiles, float4 both directions.
// ---------------------------------------------------------------------------
__global__ __launch_bounds__(256) void k_apply(const float* __restrict__ logmel,
    const float* __restrict__ ps, const int* __restrict__ xn32,
    float* __restrict__ out, float* __restrict__ outseq) {
  const int bid = blockIdx.x;
  const int b = bid / 24, c = bid % 24;
  const int tbase = c * 64;
  __shared__ float tile[64 * 81];
  __shared__ float smean[80], sistd[80];
  const int tid = threadIdx.x;
  const int n = read_n(xn32, b);
  if (tid < 80) {
    float S = ps[b * 160 + tid], S2 = ps[b * 160 + 80 + tid];
    float fn = (float)n;
    float mean = S / fn;
    float var = (S2 - fn * mean * mean) / (fn - 1.f);
    var = var < 0.f ? 0.f : var;
    smean[tid] = mean;
    sistd[tid] = 1.f / (sqrtf(var) + STD_EPS);
  }
  __syncthreads();

  for (int e = tid; e < 1280; e += 256) {      // 64 t x 20 float4-of-m
    int tt = e / 20, v = e % 20;
    int t = tbase + tt;
    int m0 = 4 * v;
    float4 val;
    if (t >= T)      val = make_float4(BLANK_V, BLANK_V, BLANK_V, BLANK_V);
    else if (t >= n) val = make_float4(0.f, 0.f, 0.f, 0.f);
    else {
      const float4 g = *(const float4*)&logmel[((size_t)b * T + t) * NMEL + m0];
      val.x = (g.x - smean[m0])     * sistd[m0];
      val.y = (g.y - smean[m0 + 1]) * sistd[m0 + 1];
      val.z = (g.z - smean[m0 + 2]) * sistd[m0 + 2];
      val.w = (g.w - smean[m0 + 3]) * sistd[m0 + 3];
    }
    float* tp = &tile[tt * 81 + m0];
    tp[0] = val.x; tp[1] = val.y; tp[2] = val.z; tp[3] = val.w;
  }
  __syncthreads();
  for (int e = tid; e < 1280; e += 256) {      // 80 m x 16 float4-of-t
    int m = e >> 4, v = e & 15;
    int tt0 = 4 * v;
    int t = tbase + tt0;
    if (t < TOUT) {
      float4 o;
      o.x = tile[(tt0    ) * 81 + m];
      o.y = tile[(tt0 + 1) * 81 + m];
      o.z = tile[(tt0 + 2) * 81 + m];
      o.w = tile[(tt0 + 3) * 81 + m];
      *(float4*)&out[((size_t)b * NMEL + m) * TOUT + t] = o;
    }
  }
  if (c == 0 && tid == 0) outseq[b] = (float)n;
}

// ---------------------------------------------------------------------------
extern "C" void kernel_launch(void* const* d_in, const int* in_sizes, int n_in,
                              void* d_out, int out_size, void* d_ws, size_t ws_size,
                              hipStream_t stream) {
  const float* x  = (const float*)d_in[0];
  const int*   xn = (const int*)d_in[1];
  const float* fb = (const float*)d_in[2];

  float* out    = (float*)d_out;
  float* outseq = out + (size_t)BATCH * NMEL * TOUT;

  float* logmel = (float*)d_ws;
  int*   lc = (int*)(logmel + LOGMEL_ELTS);
  float* wg = (float*)(lc + NMEL);                  // 80*CMAX
  float* ps = wg + NMEL * CMAX;                     // 32*160 accumulators
  unsigned short* Bf = (unsigned short*)(ps + 32 * 160);  // 10*32*64*8 bf16

  k_setup<<<720, 256, 0, stream>>>(fb, lc, wg, ps, Bf);
  k_dft  <<<BATCH * CBLK, 512, 0, stream>>>(x, lc, wg, xn, Bf, logmel, ps);
  k_apply<<<BATCH * CBLK, 256, 0, stream>>>(logmel, ps, xn, out, outseq);
}